// Round 5
// baseline (616131.104 us; speedup 1.0000x reference)
//
#include <hip/hip_runtime.h>

// RnnGenerator: C=2048, 4-layer ReLU RNN, 512 autoregressive steps = 2048
// strictly serial GEMV stages + 3-layer MLP LengthProducer.
// Round-10: round-9 two-level XCD multicast + consumer liveness watchdog.
//  - Round-9 returned an opaque harness ExceptionGroup (no compile error,
//    no pytest output, no timing) — likely infra, but a consumer hang on
//    the unverified sc0-flag-visibility assumption cannot be excluded.
//  - Watchdog: the flag gate spins <=1500 iters (~0.2 ms); on timeout the
//    wave falls back to the round-6 HW-PROVEN path (sc1 poll of done[256],
//    sc1 slice pull from the original IC buffers). Both paths stage
//    bit-identical values into LDS, so any per-wave mixture is correct,
//    and a hang is structurally impossible. Counter signature
//    disambiguates: protocol-works => FETCH_SIZE ~1e6 KB, ~4.5-5.5 ms;
//    protocol-dead => ~1.4e7 KB, ~10-12 ms (fallback every stage).
//  - Protocol (unchanged from round-9): elected wave per XCD polls done[]
//    (sc1), pulls fresh A from IC (sc1), republishes into per-XCD locA
//    with PLAIN stores (land in the XCD's single shared L2), vmcnt(0) ack,
//    then flag store. 32 local blocks gate on the flag (sc0 = L1-bypass,
//    L2-served) and pull slices with sc0 -> zero IC transactions for the
//    256-way broadcast. B (ready >=3 stages early) handled by wave1 into a
//    4-deep ring, hidden under flag-wait. Flag lines 128B-strided per XCD.
//  - All asm vector operands are ext_vector_type (HIP float4 is a struct;
//    clang cannot pass structs as asm register INPUTS).
// fp32 everywhere: states binarize to exactly {0,1} via h/(h+1e-12);
// bf16 would flip near-zero pre-activation signs (trajectory is chaotic).

#define C      2048
#define NB     256
#define NT     512
#define STEPS  512
#define NXCD   8
#define SPIN_MAX 1500

typedef unsigned long long u64;
typedef unsigned int u32;
typedef float vf4 __attribute__((ext_vector_type(4)));
typedef unsigned int vu4 __attribute__((ext_vector_type(4)));
typedef unsigned int vu2 __attribute__((ext_vector_type(2)));

// ws layout:
//   u64   lp[3][C]                  tagged LP dataflow words (48 KB)
//   float f[13*C]: inp[2][C] | hidb[2][4][C] | hraw[3][C]    (104 KB)
//   u32   ctrl region (all offsets 128B-aligned):
//     done[256]        @ ctrl+0     sc1/atomic only (cross-XCD safe)
//     cnt[8] (+pad)    @ ctrl+256   atomicAdd only, own line
//     xbf[8][32]       @ ctrl+288   per-XCD flag pair, 128B stride
//   float locA[8][2][C] @ ctrl+544  per-XCD A mirror (L2-resident)
//   float locB[8][4][C]             per-XCD B mirror, 4-deep ring
#define F_INP   0
#define F_HIDB  (2*C)
#define F_HRAW  (10*C)

__device__ __forceinline__ float wred(float v) {
#pragma unroll
  for (int off = 32; off > 0; off >>= 1) v += __shfl_down(v, off, 64);
  return v;
}

// ---- tagged u64 helpers (LengthProducer only) ----
__device__ __forceinline__ u64 pack(float val, int tag) {
  return ((u64)(unsigned)tag << 32) | (u64)__float_as_uint(val);
}
__device__ __forceinline__ void pub64(u64* p, float val, int tag) {
  __hip_atomic_store(p, pack(val, tag), __ATOMIC_RELAXED, __HIP_MEMORY_SCOPE_AGENT);
}
__device__ __forceinline__ u64 peek(u64* p) {
  return __hip_atomic_load(p, __ATOMIC_RELAXED, __HIP_MEMORY_SCOPE_AGENT);
}
__device__ __forceinline__ float val_of(u64 v) { return __uint_as_float((unsigned)v); }
__device__ __forceinline__ int   tag_of(u64 v) { return (int)(v >> 32); }

// ---- coherent access helpers (load+wait fused: no rule-#18 hazard) ----
__device__ __forceinline__ vu4 ldu4_sc1(const u32* p) {     // IC-coherent
  vu4 r;
  asm volatile("global_load_dwordx4 %0, %1, off sc1\n\t"
               "s_waitcnt vmcnt(0)"
               : "=&v"(r) : "v"(p) : "memory");
  return r;
}
__device__ __forceinline__ vu2 ld2_sc0(const u32* p) {      // L2-coherent
  vu2 r;
  asm volatile("global_load_dwordx2 %0, %1, off sc0\n\t"
               "s_waitcnt vmcnt(0)"
               : "=&v"(r) : "v"(p) : "memory");
  return r;
}
// 128B batched sc1 pull (aggregator: 8 loads, ONE drain)
__device__ __forceinline__ void pull8_sc1(const float* p,
    vf4& v0, vf4& v1, vf4& v2, vf4& v3,
    vf4& v4, vf4& v5, vf4& v6, vf4& v7) {
  asm volatile(
      "global_load_dwordx4 %0, %8, off sc1\n\t"
      "global_load_dwordx4 %1, %8, off offset:16 sc1\n\t"
      "global_load_dwordx4 %2, %8, off offset:32 sc1\n\t"
      "global_load_dwordx4 %3, %8, off offset:48 sc1\n\t"
      "global_load_dwordx4 %4, %8, off offset:64 sc1\n\t"
      "global_load_dwordx4 %5, %8, off offset:80 sc1\n\t"
      "global_load_dwordx4 %6, %8, off offset:96 sc1\n\t"
      "global_load_dwordx4 %7, %8, off offset:112 sc1\n\t"
      "s_waitcnt vmcnt(0)"
      : "=&v"(v0), "=&v"(v1), "=&v"(v2), "=&v"(v3),
        "=&v"(v4), "=&v"(v5), "=&v"(v6), "=&v"(v7)
      : "v"(p) : "memory");
}
// 128B plain republish into shared L2 + ack (release precedes flag)
__device__ __forceinline__ void push8_l2(float* p,
    vf4 v0, vf4 v1, vf4 v2, vf4 v3,
    vf4 v4, vf4 v5, vf4 v6, vf4 v7) {
  asm volatile(
      "global_store_dwordx4 %8, %0, off\n\t"
      "global_store_dwordx4 %8, %1, off offset:16\n\t"
      "global_store_dwordx4 %8, %2, off offset:32\n\t"
      "global_store_dwordx4 %8, %3, off offset:48\n\t"
      "global_store_dwordx4 %8, %4, off offset:64\n\t"
      "global_store_dwordx4 %8, %5, off offset:80\n\t"
      "global_store_dwordx4 %8, %6, off offset:96\n\t"
      "global_store_dwordx4 %8, %7, off offset:112\n\t"
      "s_waitcnt vmcnt(0)"
      :: "v"(v0), "v"(v1), "v"(v2), "v"(v3),
         "v"(v4), "v"(v5), "v"(v6), "v"(v7), "v"(p) : "memory");
}
__device__ __forceinline__ void stflag(u32* p, u32 v) {     // fire-and-forget
  asm volatile("global_store_dword %0, %1, off" :: "v"(p), "v"(v) : "memory");
}
// consumer slice pull: 2 loads, one drain — sc0 (local-L2) variant
__device__ __forceinline__ void pull2_sc0(const float* a, const float* b,
                                          vf4& va, vf4& vb) {
  asm volatile("global_load_dwordx4 %0, %2, off sc0\n\t"
               "global_load_dwordx4 %1, %3, off sc0\n\t"
               "s_waitcnt vmcnt(0)"
               : "=&v"(va), "=&v"(vb) : "v"(a), "v"(b) : "memory");
}
// and sc1 (IC) variant for the watchdog fallback (round-6 proven path)
__device__ __forceinline__ void pull2_sc1(const float* a, const float* b,
                                          vf4& va, vf4& vb) {
  asm volatile("global_load_dwordx4 %0, %2, off sc1\n\t"
               "global_load_dwordx4 %1, %3, off sc1\n\t"
               "s_waitcnt vmcnt(0)"
               : "=&v"(va), "=&v"(vb) : "v"(a), "v"(b) : "memory");
}
__device__ __forceinline__ void stf_dev(float* p, float v) {
  __hip_atomic_store(p, v, __ATOMIC_RELAXED, __HIP_MEMORY_SCOPE_AGENT);
}

// LP poll: tagged per-element (3 stages only, off the hot path)
__device__ __forceinline__ void poll1(u64* __restrict__ A, int tagA,
                                      float* __restrict__ sa, int tid) {
  u64* a = A + 4 * tid;
  u64 va0, va1, va2, va3;
  for (;;) {
    va0 = peek(a + 0); va1 = peek(a + 1); va2 = peek(a + 2); va3 = peek(a + 3);
    bool ok = (tag_of(va0) == tagA) & (tag_of(va1) == tagA)
            & (tag_of(va2) == tagA) & (tag_of(va3) == tagA);
    if (ok) break;
    __builtin_amdgcn_s_sleep(2);
  }
  float4 fa = { val_of(va0), val_of(va1), val_of(va2), val_of(va3) };
  ((float4*)sa)[tid] = fa;
}

__global__ void init_kernel(const float* __restrict__ x, u64* __restrict__ ws) {
  float* f    = (float*)(ws + 3 * C);
  u32*   ctrl = (u32*)(f + 13 * C);
  u32*   done = ctrl;
  u32*   cnt  = ctrl + 256;
  u32*   xbf  = ctrl + 288;
  int i = blockIdx.x * blockDim.x + threadIdx.x;
  if (i < C) {
    f[F_INP + i]          = 0.f;    // inp parity 0 (t=0 input) = zeros
    f[F_HIDB + 0 * C + i] = x[i];   // hid layer0 (t=-1) = x
    f[F_HIDB + 1 * C + i] = 0.f;
    f[F_HIDB + 2 * C + i] = 0.f;
    f[F_HIDB + 3 * C + i] = 0.f;
  }
  if (i < NB) done[i] = 0;
  if (i < NXCD) { cnt[i] = 0; xbf[i * 32 + 0] = 0; xbf[i * 32 + 1] = 0; }
}

__global__ __launch_bounds__(NT, 2) void rnn_persist(
    const float* __restrict__ x,
    const float* __restrict__ lp_w,  const float* __restrict__ lp_b,
    const float* __restrict__ lp_wout, const float* __restrict__ lp_bout,
    const float* __restrict__ w_ih,  const float* __restrict__ b_ih,
    const float* __restrict__ w_hh,  const float* __restrict__ b_hh,
    float* __restrict__ out, u64* __restrict__ ws)
{
  extern __shared__ float4 w3[];            // 8 waves x 2 mats x 512 f4 = 128 KB
  __shared__ __align__(16) float sh_a[C];   // 8 KB staged input vector
  __shared__ __align__(16) float sh_b[C];   // 8 KB staged hidden vector
  __shared__ int s_xcd, s_elect;

  u64*   lp    = ws;                         // 3*C tagged u64
  float* f     = (float*)(ws + 3 * C);
  float* inp   = f + F_INP;
  float* hidb  = f + F_HIDB;
  float* hraw  = f + F_HRAW;
  u32*   ctrl  = (u32*)(f + 13 * C);
  u32*   done_ = ctrl;                       // [256]
  u32*   cnt   = ctrl + 256;                 // [8] own line
  u32*   xbf   = ctrl + 288;                 // [8][32] 128B stride
  float* locA  = (float*)(ctrl + 544);       // [8][2][C], 128B-aligned
  float* locB  = locA + (size_t)NXCD * 2 * C;// [8][4][C]

  const int tid  = threadIdx.x;
  const int lane = tid & 63;
  const int wid  = tid >> 6;
  const int j    = blockIdx.x * 8 + wid;    // unit owned by this wave

  // ---------------- prime: layers 0-2 rows -> regs, layer 3 -> LDS --------
  const float4* WI = (const float4*)w_ih;
  const float4* WH = (const float4*)w_hh;
  float4 wir[3][8], whr[3][8];
#pragma unroll
  for (int l = 0; l < 3; ++l) {
    const size_t bi = (size_t)(l * C + j) * 512;
#pragma unroll
    for (int r = 0; r < 8; ++r) {
      wir[l][r] = WI[bi + r * 64 + lane];
      whr[l][r] = WH[bi + r * 64 + lane];
    }
  }
  {
    const size_t b3 = (size_t)(3 * C + j) * 512;
#pragma unroll
    for (int r = 0; r < 8; ++r) {
      w3[(wid * 2 + 0) * 512 + r * 64 + lane] = WI[b3 + r * 64 + lane];
      w3[(wid * 2 + 1) * 512 + r * 64 + lane] = WH[b3 + r * 64 + lane];
    }
  }
  float bias[4];
#pragma unroll
  for (int l = 0; l < 4; ++l) bias[l] = b_ih[l * C + j] + b_hh[l * C + j];

  // ---------------- XCD detect + aggregator election ----------------------
  if (tid == 0) {
    int xcc;
    asm volatile("s_getreg_b32 %0, hwreg(HW_REG_XCC_ID)" : "=s"(xcc));
    xcc &= (NXCD - 1);
    s_xcd = xcc;
    s_elect = (atomicAdd(&cnt[xcc], 1u) == 0u) ? 1 : 0;
  }
  __syncthreads();   // covers weight prime + election broadcast
  const int myx     = s_xcd;
  const int elected = s_elect;
  u32*   myxbf = xbf + myx * 32;
  float* myA   = locA + (size_t)myx * 2 * C;
  float* myB   = locB + (size_t)myx * 4 * C;

  // ---------------- LengthProducer (tagged dataflow, unchanged) ----------
  for (int s = 0; s < 3; ++s) {
    if (s == 0) ((float4*)sh_a)[tid] = ((const float4*)x)[tid];
    else        poll1(lp + (size_t)(s - 1) * C, s, sh_a, tid);
    __syncthreads();
    const float4* Wr  = (const float4*)(lp_w + ((size_t)s * C + j) * C);
    const float4* sa4 = (const float4*)sh_a;
    float a0 = 0, a1 = 0, a2 = 0, a3 = 0;
#pragma unroll
    for (int r = 0; r < 8; ++r) {
      float4 w = Wr[r * 64 + lane]; float4 h = sa4[r * 64 + lane];
      a0 = fmaf(w.x, h.x, a0); a1 = fmaf(w.y, h.y, a1);
      a2 = fmaf(w.z, h.z, a2); a3 = fmaf(w.w, h.w, a3);
    }
    float acc = wred((a0 + a1) + (a2 + a3));
    if (lane == 0) {
      float v = acc + lp_b[s * C + j];
      pub64(&lp[(size_t)s * C + j], (v >= 0.f) ? v : 0.2f * v, s + 1);
    }
    __syncthreads();   // sh_a reuse protection
  }

  // LP head: block 0 wave 0 polls lp[2] (tag 3), batched 8-wide.
  if (blockIdx.x == 0 && wid == 0) {
    float p = 0.f;
#pragma unroll
    for (int g = 0; g < 4; ++g) {
      u64 v[8];
      for (;;) {
        bool ok = true;
#pragma unroll
        for (int r = 0; r < 8; ++r)
          v[r] = peek(&lp[2 * C + (g * 8 + r) * 64 + lane]);
#pragma unroll
        for (int r = 0; r < 8; ++r) ok &= (tag_of(v[r]) == 3);
        if (ok) break;
        __builtin_amdgcn_s_sleep(2);
      }
#pragma unroll
      for (int r = 0; r < 8; ++r)
        p = fmaf(lp_wout[(g * 8 + r) * 64 + lane], val_of(v[r]), p);
    }
    p = wred(p);
    if (lane == 0) {
      float l = fabsf(p + lp_bout[0]);
      out[(size_t)STEPS * C] = fminf(l, 0.9999f);
    }
  }

  // ---- pre-loop: elected wave1 seeds B(0) = hidb[parity0][layer0] --------
  if (elected && wid == 1) {
    vf4 t0, t1, t2, t3, t4, t5, t6, t7;
    pull8_sc1(hidb + 32 * lane, t0, t1, t2, t3, t4, t5, t6, t7);
    push8_l2(myB + 0 * C + 32 * lane, t0, t1, t2, t3, t4, t5, t6, t7);
    if (lane == 0) stflag(myxbf + 1, 1u);
  }

  // ---------------- 512 steps x 4 layers, XCD-multicast dataflow ----------
  const int q = (tid + 2 * blockIdx.x) & (NT - 1);  // stagger local lines

  for (int t = 0; t < STEPS; ++t) {
    const int p = t & 1;
#pragma unroll
    for (int l = 0; l < 4; ++l) {
      const u32 tgt = (u32)(4 * t + l);    // stage index we depend on

      if (elected && wid == 0) {
        // -------- aggregate A(tgt): poll done[], pull IC, republish L2 ----
        for (;;) {
          vu4 v = ldu4_sc1(done_ + 4 * lane);
          bool ok = (v.x >= tgt) & (v.y >= tgt) & (v.z >= tgt) & (v.w >= tgt);
          if (__all(ok)) break;
          __builtin_amdgcn_s_sleep(1);
        }
        const float* Asrc = (l == 0) ? (inp + (size_t)p * C)
                                     : (hraw + (size_t)(l - 1) * C);
        vf4 t0, t1, t2, t3, t4, t5, t6, t7;
        pull8_sc1(Asrc + 32 * lane, t0, t1, t2, t3, t4, t5, t6, t7);
        push8_l2(myA + (size_t)(tgt & 1) * C + 32 * lane,
                 t0, t1, t2, t3, t4, t5, t6, t7);            // ack inside
        if (lane == 0) stflag(myxbf + 0, tgt + 1);
      }
      if (elected && wid == 1) {
        // -------- republish B(tgt+1) into 4-deep ring (hidden work) -------
        // Source published at stage tgt-3 (visible: we passed last stage's
        // gate => done>=tgt-1 globally => stage tgt-2 stores drained).
        // Ring slot (tgt+1)&3 held B(tgt-3); its readers finished stage
        // tgt-3 by the same transitivity.
        const u32 s1 = tgt + 1;
        const int t1i = (int)(s1 >> 2), l1 = (int)(s1 & 3), p1 = t1i & 1;
        vf4 t0, t1, t2, t3, t4, t5, t6, t7;
        pull8_sc1(hidb + (size_t)(p1 * 4 + l1) * C + 32 * lane,
                  t0, t1, t2, t3, t4, t5, t6, t7);
        push8_l2(myB + (size_t)(s1 & 3) * C + 32 * lane,
                 t0, t1, t2, t3, t4, t5, t6, t7);            // ack inside
        if (lane == 0) stflag(myxbf + 1, s1 + 1);
      }

      // -------- consume: flag gate with liveness watchdog -----------------
      int direct = 0;
      if (lane == 0) {
        int spins = 0;
        for (;;) {
          vu2 v = ld2_sc0(myxbf);
          if ((v.x >= tgt + 1) & (v.y >= tgt + 1)) break;
          if (++spins >= SPIN_MAX) { direct = 1; break; }
          __builtin_amdgcn_s_sleep(2);
        }
      }
      direct = __shfl(direct, 0, 64);
      if (!direct) {
        // fast path: slices from the per-XCD local-L2 mirror (sc0)
        const float* A = myA + (size_t)(tgt & 1) * C;
        const float* B = myB + (size_t)(tgt & 3) * C;
        vf4 va, vb;
        pull2_sc0(A + 4 * q, B + 4 * q, va, vb);
        ((vf4*)sh_a)[q] = va;
        ((vf4*)sh_b)[q] = vb;
      } else {
        // watchdog fallback: round-6 HW-proven path. Whole wave polls the
        // 256 done counters (sc1), then pulls slices from the IC source.
        for (;;) {
          vu4 v = ldu4_sc1(done_ + 4 * lane);
          bool ok = (v.x >= tgt) & (v.y >= tgt) & (v.z >= tgt) & (v.w >= tgt);
          if (__all(ok)) break;
          __builtin_amdgcn_s_sleep(2);
        }
        const float* A = (l == 0) ? (inp + (size_t)p * C)
                                  : (hraw + (size_t)(l - 1) * C);
        const float* B = hidb + (size_t)(p * 4 + l) * C;
        vf4 va, vb;
        pull2_sc1(A + 4 * q, B + 4 * q, va, vb);
        ((vf4*)sh_a)[q] = va;
        ((vf4*)sh_b)[q] = vb;
      }
      __syncthreads();

      const float4* sa4 = (const float4*)sh_a;
      const float4* sb4 = (const float4*)sh_b;
      float a0 = 0, a1 = 0, a2 = 0, a3 = 0;
      if (l < 3) {
#pragma unroll
        for (int r = 0; r < 8; ++r) {
          float4 h = sa4[r * 64 + lane]; float4 w = wir[l][r];
          a0 = fmaf(w.x, h.x, a0); a1 = fmaf(w.y, h.y, a1);
          a2 = fmaf(w.z, h.z, a2); a3 = fmaf(w.w, h.w, a3);
          float4 g = sb4[r * 64 + lane]; float4 v = whr[l][r];
          a0 = fmaf(v.x, g.x, a0); a1 = fmaf(v.y, g.y, a1);
          a2 = fmaf(v.z, g.z, a2); a3 = fmaf(v.w, g.w, a3);
        }
      } else {
#pragma unroll
        for (int r = 0; r < 8; ++r) {
          float4 h = sa4[r * 64 + lane]; float4 w = w3[(wid * 2 + 0) * 512 + r * 64 + lane];
          a0 = fmaf(w.x, h.x, a0); a1 = fmaf(w.y, h.y, a1);
          a2 = fmaf(w.z, h.z, a2); a3 = fmaf(w.w, h.w, a3);
          float4 g = sb4[r * 64 + lane]; float4 v = w3[(wid * 2 + 1) * 512 + r * 64 + lane];
          a0 = fmaf(v.x, g.x, a0); a1 = fmaf(v.y, g.y, a1);
          a2 = fmaf(v.z, g.z, a2); a3 = fmaf(v.w, g.w, a3);
        }
      }
      float acc = wred((a0 + a1) + (a2 + a3));

      if (lane == 0) {
        float pre = acc + bias[l];
        float h   = fmaxf(pre, 0.f);
        float bin = h / (h + 1e-12f);
        if (l < 3) {
          stf_dev(&hraw[(size_t)l * C + j], h);                    // critical
          stf_dev(&hidb[(size_t)((p ^ 1) * 4 + l) * C + j], bin);
        } else {
          stf_dev(&inp[(size_t)(p ^ 1) * C + j], bin);             // critical
          stf_dev(&hidb[(size_t)((p ^ 1) * 4 + 3) * C + j], bin);
          out[(size_t)t * C + j] = bin;
        }
      }
      // Release: hipcc drains vmcnt(0) before s_barrier, so all waves'
      // agent-scope stores are visible when any thread passes this barrier.
      // Also protects sh_a/sh_b reuse.
      __syncthreads();
      if (tid == 0)
        __hip_atomic_store(&done_[blockIdx.x], tgt + 1,
                           __ATOMIC_RELAXED, __HIP_MEMORY_SCOPE_AGENT);
    }
  }
}

extern "C" void kernel_launch(void* const* d_in, const int* in_sizes, int n_in,
                              void* d_out, int out_size, void* d_ws, size_t ws_size,
                              hipStream_t stream) {
  const float* x       = (const float*)d_in[0];
  const float* lp_w    = (const float*)d_in[1];
  const float* lp_b    = (const float*)d_in[2];
  const float* lp_wout = (const float*)d_in[3];
  const float* lp_bout = (const float*)d_in[4];
  const float* w_ih    = (const float*)d_in[5];
  const float* b_ih    = (const float*)d_in[6];
  const float* w_hh    = (const float*)d_in[7];
  const float* b_hh    = (const float*)d_in[8];
  float* out = (float*)d_out;
  u64*   ws  = (u64*)d_ws;

  hipLaunchKernelGGL(init_kernel, dim3(8), dim3(256), 0, stream, x, ws);
  hipLaunchKernelGGL(rnn_persist, dim3(NB), dim3(NT),
                     8 * 2 * 512 * sizeof(float4) /* 128 KB dyn LDS */, stream,
                     x, lp_w, lp_b, lp_wout, lp_bout,
                     w_ih, b_ih, w_hh, b_hh, out, ws);
}

// Round 6
// 13467.996 us; speedup vs baseline: 45.7478x; 45.7478x over previous
//
#include <hip/hip_runtime.h>

// RnnGenerator: C=2048, 4-layer ReLU RNN, 512 autoregressive steps = 2048
// strictly serial GEMV stages + 3-layer MLP LengthProducer.
// Round-11: round-6 proven transport + B-operand derived locally.
//  - Round-10 verdict: the per-XCD "plain store -> sc0 load" multicast
//    channel NEVER delivers (watchdog fired all 2048 stages, 301us/stage).
//    Abandoned. Transport reverts to round-6's HW-proven sc1 protocol.
//  - New insight: B(s) = bin(V(s-3)) where V(s-3) is the SAME raw vector
//    this block pulled as A three stages earlier (holds across the
//    t-boundary too: B(4t+3)=bin(h3(t-1))=bin(A(4t))). So B never crosses
//    the fabric: a 4-slot LDS ring of locally-binarized A-pulls replaces
//    the global hidb/inp entirely. bin = h/(h+1e-12f) exact fp32 division,
//    deterministic -> bit-identical to producer-side binarization.
//    Producers publish ONE raw h per unit per stage (hbuf[2][C], slot l&1).
//    Cuts per-stage IC transactions ~131K (B pulls) + half producer stores.
//  - Ring slot = l (since s&3 == l). B slot = (l+1)&3. A_use for l==0 is
//    bins[0] (inp = bin(h3)); else sh_a (raw). Bootstrap: bins[1]=x raw
//    (B(0)=hid0[0]=x), bins[0/2/3]=0 (hid0[1..3]=0, and B(3)=bins[0]
//    still 0 because stage 0 skips staging).
//  - hidb gone -> LDS freed -> layer-3 weights now in registers like
//    layers 0-2 (256 weight regs/lane; 192 already proven no-spill).
//    LDS 144KB -> 40KB, no dynamic LDS.
// fp32 everywhere: states binarize via h/(h+1e-12f); exactness matters
// (h in (0,1e-5) gives partial bins ~84x per run; trajectory is chaotic).

#define C      2048
#define NB     256
#define NT     512
#define STEPS  512

typedef unsigned long long u64;
typedef unsigned int u32;
typedef float vf4 __attribute__((ext_vector_type(4)));
typedef unsigned int vu4 __attribute__((ext_vector_type(4)));

// ws layout:
//   u64   lp[3][C]      tagged LP dataflow words (48 KB)
//   float hbuf[2][C]    raw h publish ring, slot = l&1 (16 KB)
//   u32   done[NB]      per-block completed-stage counters (1 KB)

__device__ __forceinline__ float wred(float v) {
#pragma unroll
  for (int off = 32; off > 0; off >>= 1) v += __shfl_down(v, off, 64);
  return v;
}

// ---- tagged u64 helpers (LengthProducer only) ----
__device__ __forceinline__ u64 pack(float val, int tag) {
  return ((u64)(unsigned)tag << 32) | (u64)__float_as_uint(val);
}
__device__ __forceinline__ void pub64(u64* p, float val, int tag) {
  __hip_atomic_store(p, pack(val, tag), __ATOMIC_RELAXED, __HIP_MEMORY_SCOPE_AGENT);
}
__device__ __forceinline__ u64 peek(u64* p) {
  return __hip_atomic_load(p, __ATOMIC_RELAXED, __HIP_MEMORY_SCOPE_AGENT);
}
__device__ __forceinline__ float val_of(u64 v) { return __uint_as_float((unsigned)v); }
__device__ __forceinline__ int   tag_of(u64 v) { return (int)(v >> 32); }

// ---- IC-coherent access (load+wait fused; ext_vector operands) ----
__device__ __forceinline__ vu4 ldu4_sc1(const u32* p) {
  vu4 r;
  asm volatile("global_load_dwordx4 %0, %1, off sc1\n\t"
               "s_waitcnt vmcnt(0)"
               : "=&v"(r) : "v"(p) : "memory");
  return r;
}
__device__ __forceinline__ vf4 ldf4_sc1(const float* p) {
  vf4 r;
  asm volatile("global_load_dwordx4 %0, %1, off sc1\n\t"
               "s_waitcnt vmcnt(0)"
               : "=&v"(r) : "v"(p) : "memory");
  return r;
}
__device__ __forceinline__ void stf_dev(float* p, float v) {
  __hip_atomic_store(p, v, __ATOMIC_RELAXED, __HIP_MEMORY_SCOPE_AGENT);
}

// LP poll: tagged per-element (3 stages only, off the hot path)
__device__ __forceinline__ void poll1(u64* __restrict__ A, int tagA,
                                      float* __restrict__ sa, int tid) {
  u64* a = A + 4 * tid;
  u64 va0, va1, va2, va3;
  for (;;) {
    va0 = peek(a + 0); va1 = peek(a + 1); va2 = peek(a + 2); va3 = peek(a + 3);
    bool ok = (tag_of(va0) == tagA) & (tag_of(va1) == tagA)
            & (tag_of(va2) == tagA) & (tag_of(va3) == tagA);
    if (ok) break;
    __builtin_amdgcn_s_sleep(2);
  }
  float4 fa = { val_of(va0), val_of(va1), val_of(va2), val_of(va3) };
  ((float4*)sa)[tid] = fa;
}

__global__ void init_kernel(u64* __restrict__ ws) {
  u64*   lp   = ws;
  float* hbuf = (float*)(ws + 3 * C);
  u32*   done = (u32*)(hbuf + 2 * C);
  int i = blockIdx.x * blockDim.x + threadIdx.x;
  if (i < C) { lp[i] = 0; lp[C + i] = 0; lp[2 * C + i] = 0; }
  if (i < NB) done[i] = 0;
}

__global__ __launch_bounds__(NT, 2) void rnn_persist(
    const float* __restrict__ x,
    const float* __restrict__ lp_w,  const float* __restrict__ lp_b,
    const float* __restrict__ lp_wout, const float* __restrict__ lp_bout,
    const float* __restrict__ w_ih,  const float* __restrict__ b_ih,
    const float* __restrict__ w_hh,  const float* __restrict__ b_hh,
    float* __restrict__ out, u64* __restrict__ ws)
{
  __shared__ __align__(16) float sh_a[C];      // 8 KB raw A stage
  __shared__ __align__(16) float bins[4][C];   // 32 KB binarized ring

  u64*   lp    = ws;
  float* hbuf  = (float*)(ws + 3 * C);         // [2][C]
  u32*   done_ = (u32*)(hbuf + 2 * C);         // [256]

  const int tid  = threadIdx.x;
  const int lane = tid & 63;
  const int wid  = tid >> 6;
  const int j    = blockIdx.x * 8 + wid;       // unit owned by this wave

  // ---------------- prime: ALL 4 layers' rows -> registers ----------------
  const float4* WI = (const float4*)w_ih;
  const float4* WH = (const float4*)w_hh;
  float4 wir[4][8], whr[4][8];
#pragma unroll
  for (int l = 0; l < 4; ++l) {
    const size_t bi = (size_t)(l * C + j) * 512;
#pragma unroll
    for (int r = 0; r < 8; ++r) {
      wir[l][r] = WI[bi + r * 64 + lane];
      whr[l][r] = WH[bi + r * 64 + lane];
    }
  }
  float bias[4];
#pragma unroll
  for (int l = 0; l < 4; ++l) bias[l] = b_ih[l * C + j] + b_hh[l * C + j];

  // ---------------- LengthProducer (tagged dataflow, proven) -------------
  for (int s = 0; s < 3; ++s) {
    if (s == 0) ((float4*)sh_a)[tid] = ((const float4*)x)[tid];
    else        poll1(lp + (size_t)(s - 1) * C, s, sh_a, tid);
    __syncthreads();
    const float4* Wr  = (const float4*)(lp_w + ((size_t)s * C + j) * C);
    const float4* sa4 = (const float4*)sh_a;
    float a0 = 0, a1 = 0, a2 = 0, a3 = 0;
#pragma unroll
    for (int r = 0; r < 8; ++r) {
      float4 w = Wr[r * 64 + lane]; float4 h = sa4[r * 64 + lane];
      a0 = fmaf(w.x, h.x, a0); a1 = fmaf(w.y, h.y, a1);
      a2 = fmaf(w.z, h.z, a2); a3 = fmaf(w.w, h.w, a3);
    }
    float acc = wred((a0 + a1) + (a2 + a3));
    if (lane == 0) {
      float v = acc + lp_b[s * C + j];
      pub64(&lp[(size_t)s * C + j], (v >= 0.f) ? v : 0.2f * v, s + 1);
    }
    __syncthreads();   // sh_a reuse protection
  }

  // LP head: block 0 wave 0 polls lp[2] (tag 3), batched 8-wide.
  if (blockIdx.x == 0 && wid == 0) {
    float p = 0.f;
#pragma unroll
    for (int g = 0; g < 4; ++g) {
      u64 v[8];
      for (;;) {
        bool ok = true;
#pragma unroll
        for (int r = 0; r < 8; ++r)
          v[r] = peek(&lp[2 * C + (g * 8 + r) * 64 + lane]);
#pragma unroll
        for (int r = 0; r < 8; ++r) ok &= (tag_of(v[r]) == 3);
        if (ok) break;
        __builtin_amdgcn_s_sleep(2);
      }
#pragma unroll
      for (int r = 0; r < 8; ++r)
        p = fmaf(lp_wout[(g * 8 + r) * 64 + lane], val_of(v[r]), p);
    }
    p = wred(p);
    if (lane == 0) {
      float l = fabsf(p + lp_bout[0]);
      out[(size_t)STEPS * C] = fminf(l, 0.9999f);
    }
  }

  // ---------------- bins bootstrap ----------------------------------------
  // B(0)=hid0[0]=x (RAW); B(1)=bins[2]=0; B(2)=bins[3]=0; B(3)=bins[0]=0.
  {
    vf4 z = {0.f, 0.f, 0.f, 0.f};
    ((vf4*)bins[0])[tid] = z;
    ((vf4*)bins[2])[tid] = z;
    ((vf4*)bins[3])[tid] = z;
    ((vf4*)bins[1])[tid] = ((const vf4*)x)[tid];
  }
  // (stage-0 barrier below publishes these to all waves)

  // ---------------- 512 steps x 4 layers, flag-gated pull -----------------
  const int q = (tid + 2 * blockIdx.x) & (NT - 1);  // stagger hot lines

  for (int t = 0; t < STEPS; ++t) {
#pragma unroll
    for (int l = 0; l < 4; ++l) {
      const int s = 4 * t + l;                 // stage index; s&3 == l

      if (l > 0 || t > 0) {
        // A readiness: wave 0 polls the 256 per-block stage counters.
        if (tid < 64) {
          for (;;) {
            vu4 v = ldu4_sc1(done_ + 4 * lane);
            bool ok = (v.x >= (u32)s) & (v.y >= (u32)s)
                    & (v.z >= (u32)s) & (v.w >= (u32)s);
            if (__all(ok)) break;
            __builtin_amdgcn_s_sleep(2);
          }
        }
        __syncthreads();
        // pull V(s) = h(s-1) from hbuf[(s-1)&1]; stage raw + binarized.
        const int hs = (l == 0) ? 1 : ((l - 1) & 1);
        vf4 va = ldf4_sc1(hbuf + (size_t)hs * C + 4 * q);
        ((vf4*)sh_a)[q] = va;
        vf4 vb;
        vb.x = va.x / (va.x + 1e-12f);
        vb.y = va.y / (va.y + 1e-12f);
        vb.z = va.z / (va.z + 1e-12f);
        vb.w = va.w / (va.w + 1e-12f);
        ((vf4*)bins[l])[q] = vb;               // ring slot s&3 == l
      }
      __syncthreads();

      const float4* sa4 = (l == 0) ? (const float4*)bins[0]
                                   : (const float4*)sh_a;
      const float4* sb4 = (const float4*)bins[(l + 1) & 3];
      float a0 = 0, a1 = 0, a2 = 0, a3 = 0;
#pragma unroll
      for (int r = 0; r < 8; ++r) {
        float4 h = sa4[r * 64 + lane]; float4 w = wir[l][r];
        a0 = fmaf(w.x, h.x, a0); a1 = fmaf(w.y, h.y, a1);
        a2 = fmaf(w.z, h.z, a2); a3 = fmaf(w.w, h.w, a3);
        float4 g = sb4[r * 64 + lane]; float4 v = whr[l][r];
        a0 = fmaf(v.x, g.x, a0); a1 = fmaf(v.y, g.y, a1);
        a2 = fmaf(v.z, g.z, a2); a3 = fmaf(v.w, g.w, a3);
      }
      float acc = wred((a0 + a1) + (a2 + a3));

      if (lane == 0) {
        float pre = acc + bias[l];
        float h   = fmaxf(pre, 0.f);
        stf_dev(&hbuf[(size_t)(l & 1) * C + j], h);   // publish RAW h only
        if (l == 3) out[(size_t)t * C + j] = h / (h + 1e-12f);
      }
      // Release: hipcc drains vmcnt(0) before s_barrier -> all waves'
      // agent-scope stores are visible before done is bumped. Also
      // protects sh_a/bins reuse.
      __syncthreads();
      if (tid == 0)
        __hip_atomic_store(&done_[blockIdx.x], (u32)(s + 1),
                           __ATOMIC_RELAXED, __HIP_MEMORY_SCOPE_AGENT);
    }
  }
}

extern "C" void kernel_launch(void* const* d_in, const int* in_sizes, int n_in,
                              void* d_out, int out_size, void* d_ws, size_t ws_size,
                              hipStream_t stream) {
  const float* x       = (const float*)d_in[0];
  const float* lp_w    = (const float*)d_in[1];
  const float* lp_b    = (const float*)d_in[2];
  const float* lp_wout = (const float*)d_in[3];
  const float* lp_bout = (const float*)d_in[4];
  const float* w_ih    = (const float*)d_in[5];
  const float* b_ih    = (const float*)d_in[6];
  const float* w_hh    = (const float*)d_in[7];
  const float* b_hh    = (const float*)d_in[8];
  float* out = (float*)d_out;
  u64*   ws  = (u64*)d_ws;

  hipLaunchKernelGGL(init_kernel, dim3(8), dim3(256), 0, stream, ws);
  hipLaunchKernelGGL(rnn_persist, dim3(NB), dim3(NT), 0, stream,
                     x, lp_w, lp_b, lp_wout, lp_bout,
                     w_ih, b_ih, w_hh, b_hh, out, ws);
}